// Round 1
// baseline (432.097 us; speedup 1.0000x reference)
//
#include <hip/hip_runtime.h>
#include <math.h>

#define CNUM 20
#define KNUM 64
#define DDIM 256

static __device__ __forceinline__ float shfl_xor_f(float v, int m) {
    return __shfl_xor(v, m, 64);
}

// ---------------- K0: per-(c,k) stats: mu2, tau, log(tau), valid; rstd ----------------
__global__ void k_prep(const float* __restrict__ mu, const float* __restrict__ exp_temp,
                       const float* __restrict__ runa, const float* __restrict__ runb,
                       const float* __restrict__ stdv,
                       float* __restrict__ mu2, float* __restrict__ tauv,
                       float* __restrict__ ltau, float* __restrict__ vldf,
                       float* __restrict__ rstd)
{
    const int tid = threadIdx.x, w = tid >> 6, lane = tid & 63;
    if (blockIdx.x == 0) rstd[tid] = 1.0f / stdv[tid];   // blockDim==DDIM==256
    const int ck = blockIdx.x * 4 + w;
    if (ck >= CNUM * KNUM) return;
    const float4 v = *(const float4*)(mu + (size_t)ck * DDIM + lane * 4);
    float s = v.x * v.x + v.y * v.y + v.z * v.z + v.w * v.w;
#pragma unroll
    for (int off = 32; off > 0; off >>= 1) s += shfl_xor_f(s, off);
    if (lane == 0) {
        mu2[ck] = s;
        const float e = exp_temp[ck];
        const float t = 100.0f / (1.0f + __expf(-0.5f * e)) + 0.01f;
        tauv[ck] = t;
        ltau[ck] = logf(t);
        const int c = ck >> 6;
        const float thr = runb[c] * (0.5f / (float)KNUM);
        vldf[ck] = (runa[ck] > thr) ? 1.0f : 0.0f;
    }
}

// ---------------- K1: per-block class histogram ----------------
__global__ void k_hist(const int* __restrict__ labels, int N, int* __restrict__ bc)
{
    __shared__ int h[CNUM];
    const int tid = threadIdx.x;
    if (tid < CNUM) h[tid] = 0;
    __syncthreads();
    for (int i = blockIdx.x * blockDim.x + tid; i < N; i += gridDim.x * blockDim.x)
        atomicAdd(&h[labels[i]], 1);
    __syncthreads();
    if (tid < CNUM) bc[blockIdx.x * CNUM + tid] = h[tid];
}

// ---------------- K2: counts, padded class offsets, per-block scatter bases ----------------
__global__ void k_scan(const int* __restrict__ bc, int nb, int* __restrict__ cnt,
                       int* __restrict__ ps, int* __restrict__ sb)
{
    const int t = threadIdx.x;
    if (t < CNUM) {
        int s = 0;
        for (int b = 0; b < nb; b++) s += bc[b * CNUM + t];
        cnt[t] = s;
    }
    __syncthreads();
    if (t == 0) {
        int run = 0;
        for (int c = 0; c < CNUM; c++) { ps[c] = run; run += (cnt[c] + 63) & ~63; }
        ps[CNUM] = run;
    }
    __syncthreads();
    if (t < CNUM) {
        int run = ps[t];
        for (int b = 0; b < nb; b++) { sb[b * CNUM + t] = run; run += bc[b * CNUM + t]; }
    }
}

// ---------------- K3: scatter sample ids into class-sorted padded index array ----------------
__global__ void k_scatter(const int* __restrict__ labels, int N, const int* __restrict__ sb,
                          int* __restrict__ idx)
{
    __shared__ int cur[CNUM];
    const int tid = threadIdx.x;
    if (tid < CNUM) cur[tid] = sb[blockIdx.x * CNUM + tid];
    __syncthreads();
    for (int i = blockIdx.x * blockDim.x + tid; i < N; i += gridDim.x * blockDim.x) {
        const int c = labels[i];
        const int p = atomicAdd(&cur[c], 1);
        idx[p] = i;
    }
}

// ---------------- K4: main — 64 samples/block, one class/block ----------------
__global__ __launch_bounds__(256, 2)
void k_main(const float* __restrict__ data, const float* __restrict__ mu,
            const float* __restrict__ med, const float* __restrict__ rstd,
            const float* __restrict__ mu2, const float* __restrict__ tauv,
            const float* __restrict__ ltau, const float* __restrict__ vldf,
            const int* __restrict__ idx, const int* __restrict__ ps,
            float* __restrict__ blockpart)
{
    __shared__ float part[4 * 64 * 64];   // [w][m][k^swz] = xq - 2*partial_dot, 64 KB
    const int tid = threadIdx.x, w = tid >> 6, lane = tid & 63;
    const int g = blockIdx.x;
    const int slot0 = g * 64;
    const int padtot = ps[CNUM];
    if (slot0 >= padtot) { if (tid == 0) blockpart[g] = 0.f; return; }
    int c = 0;
    while (c + 1 < CNUM && slot0 >= ps[c + 1]) ++c;

    // ---- phase 1: each wave owns d-chunk [w*64, w*64+64); lane = sample m ----
    const int n = idx[slot0 + lane];
    const float act = (n >= 0) ? 1.0f : 0.0f;
    const int nn = (n >= 0) ? n : 0;
    const float* __restrict__ xrow = data + (size_t)nn * DDIM + w * 64;

    float xr[64];
    float xq;
    {
        float q0 = 0.f, q1 = 0.f, q2 = 0.f, q3 = 0.f;
#pragma unroll
        for (int j4 = 0; j4 < 16; j4++) {
            const float4 v = *(const float4*)(xrow + 4 * j4);
            const int d = w * 64 + 4 * j4;
            const float a0 = act * ((v.x - med[d + 0]) * rstd[d + 0]);
            const float a1 = act * ((v.y - med[d + 1]) * rstd[d + 1]);
            const float a2 = act * ((v.z - med[d + 2]) * rstd[d + 2]);
            const float a3 = act * ((v.w - med[d + 3]) * rstd[d + 3]);
            xr[4 * j4 + 0] = a0; xr[4 * j4 + 1] = a1;
            xr[4 * j4 + 2] = a2; xr[4 * j4 + 3] = a3;
            q0 = fmaf(a0, a0, q0); q1 = fmaf(a1, a1, q1);
            q2 = fmaf(a2, a2, q2); q3 = fmaf(a3, a3, q3);
        }
        xq = (q0 + q1) + (q2 + q3);
    }

    // mu chunk pointers are wave-uniform -> scalar (SMEM) loads, FMA = v_fmac v,s,v
    const float* __restrict__ mub = mu + ((size_t)c * KNUM) * DDIM + w * 64;
    for (int k = 0; k < KNUM; k++) {
        const float* __restrict__ mp = mub + (size_t)k * DDIM;
        float b0 = 0.f, b1 = 0.f, b2 = 0.f, b3 = 0.f, b4 = 0.f, b5 = 0.f, b6 = 0.f, b7 = 0.f;
#pragma unroll
        for (int j8 = 0; j8 < 8; j8++) {
            b0 = fmaf(xr[8 * j8 + 0], mp[8 * j8 + 0], b0);
            b1 = fmaf(xr[8 * j8 + 1], mp[8 * j8 + 1], b1);
            b2 = fmaf(xr[8 * j8 + 2], mp[8 * j8 + 2], b2);
            b3 = fmaf(xr[8 * j8 + 3], mp[8 * j8 + 3], b3);
            b4 = fmaf(xr[8 * j8 + 4], mp[8 * j8 + 4], b4);
            b5 = fmaf(xr[8 * j8 + 5], mp[8 * j8 + 5], b5);
            b6 = fmaf(xr[8 * j8 + 6], mp[8 * j8 + 6], b6);
            b7 = fmaf(xr[8 * j8 + 7], mp[8 * j8 + 7], b7);
        }
        const float acc = ((b0 + b1) + (b2 + b3)) + ((b4 + b5) + (b6 + b7));
        // XOR swizzle: writes (lanes=m) and reads (lanes=k) both bank-conflict-free
        part[(w * 64 + lane) * 64 + (k ^ (lane & 31))] = fmaf(-2.0f, acc, xq);
    }
    __syncthreads();

    // ---- phase 2: lane = k; wave w handles samples m in [w*16, w*16+16) ----
    const int ckb = c * KNUM;
    const float m2 = mu2[ckb + lane];
    const float tk = tauv[ckb + lane];
    const float lt = ltau[ckb + lane];
    const float vm = vldf[ckb + lane];
    float wacc = 0.f;
#pragma unroll 1
    for (int mi = 0; mi < 16; mi++) {
        const int m = w * 16 + mi;
        const int nm = idx[slot0 + m];
        if (nm < 0) continue;
        const int sw = lane ^ (m & 31);
        float d2 = m2 + part[(0 * 64 + m) * 64 + sw] + part[(1 * 64 + m) * 64 + sw]
                      + part[(2 * 64 + m) * 64 + sw] + part[(3 * 64 + m) * 64 + sw];
        d2 = fmaxf(d2, 0.f);
        const float dist = -6.25f * sqrtf(d2);          // 100/sqrt(256)
        const float sim = (vm > 0.5f) ? dist : -1.0e12f;
        const float logit = 0.5f * sim;
        float mx = logit;
#pragma unroll
        for (int off = 32; off > 0; off >>= 1) mx = fmaxf(mx, shfl_xor_f(mx, off));
        const float e = __expf(logit - mx);
        const float lp = sim / tk - lt;
        float se = e, sl = e * lp;
#pragma unroll
        for (int off = 32; off > 0; off >>= 1) { se += shfl_xor_f(se, off); sl += shfl_xor_f(sl, off); }
        wacc -= sl / se;
    }
    __syncthreads();
    if (lane == 0) part[w] = wacc;
    __syncthreads();
    if (tid == 0) blockpart[g] = ((part[0] + part[1]) + (part[2] + part[3]));
}

// ---------------- K5: deterministic per-class reduce -> loss ----------------
__global__ void k_final(const float* __restrict__ blockpart, const int* __restrict__ ps,
                        const int* __restrict__ cnt, float* __restrict__ out)
{
    __shared__ float seg[CNUM];
    const int t = threadIdx.x;
    if (t < CNUM) {
        float s = 0.f;
        const int b0 = ps[t] >> 6, b1 = ps[t + 1] >> 6;
        for (int b = b0; b < b1; b++) s += blockpart[b];
        seg[t] = s;
    }
    __syncthreads();
    if (t == 0) {
        float loss = 0.f;
        for (int c = 0; c < CNUM; c++) {
            const float cc = (float)cnt[c];
            if (cc > 0.f) loss += seg[c] / fmaxf(cc, 1.0f);
        }
        out[0] = loss;
    }
}

extern "C" void kernel_launch(void* const* d_in, const int* in_sizes, int n_in,
                              void* d_out, int out_size, void* d_ws, size_t ws_size,
                              hipStream_t stream)
{
    const float* data     = (const float*)d_in[0];
    const int*   labels   = (const int*)d_in[1];
    const float* mu       = (const float*)d_in[2];
    const float* exp_temp = (const float*)d_in[3];
    const float* med      = (const float*)d_in[4];
    const float* stdv     = (const float*)d_in[5];
    const float* runa     = (const float*)d_in[6];
    const float* runb     = (const float*)d_in[7];
    float* out = (float*)d_out;
    const int N = in_sizes[0] / DDIM;

    char* w = (char*)d_ws;
    float* mu2  = (float*)w; w += (size_t)CNUM * KNUM * 4;
    float* tauv = (float*)w; w += (size_t)CNUM * KNUM * 4;
    float* ltau = (float*)w; w += (size_t)CNUM * KNUM * 4;
    float* vldf = (float*)w; w += (size_t)CNUM * KNUM * 4;
    float* rstd = (float*)w; w += (size_t)DDIM * 4;
    int* bc  = (int*)w; w += (size_t)256 * CNUM * 4;
    int* sb  = (int*)w; w += (size_t)256 * CNUM * 4;
    int* cnt = (int*)w; w += 64 * 4;
    int* ps  = (int*)w; w += 64 * 4;
    const int idx_slots = N + CNUM * 64;
    int* idx = (int*)w; w += (size_t)idx_slots * 4;
    const int NB = (idx_slots + 63) / 64;
    float* bp = (float*)w; w += (size_t)NB * 4;

    k_prep<<<dim3((CNUM * KNUM + 3) / 4), dim3(256), 0, stream>>>(
        mu, exp_temp, runa, runb, stdv, mu2, tauv, ltau, vldf, rstd);
    k_hist<<<dim3(256), dim3(256), 0, stream>>>(labels, N, bc);
    k_scan<<<dim3(1), dim3(64), 0, stream>>>(bc, 256, cnt, ps, sb);
    hipMemsetAsync(idx, 0xFF, (size_t)idx_slots * 4, stream);   // idx = -1 (padding)
    k_scatter<<<dim3(256), dim3(256), 0, stream>>>(labels, N, sb, idx);
    k_main<<<dim3(NB), dim3(256), 0, stream>>>(
        data, mu, med, rstd, mu2, tauv, ltau, vldf, idx, ps, bp);
    k_final<<<dim3(1), dim3(32), 0, stream>>>(bp, ps, cnt, out);
}

// Round 2
// 121.687 us; speedup vs baseline: 3.5509x; 3.5509x over previous
//
#include <hip/hip_runtime.h>
#include <math.h>

#define CNUM 20
#define KNUM 64
#define DDIM 256

typedef __attribute__((ext_vector_type(8))) short short8;
typedef __attribute__((ext_vector_type(8))) unsigned short u16x8;
typedef __attribute__((ext_vector_type(4))) float f32x4;

static __device__ __forceinline__ float shfl_xor_f(float v, int m) {
    return __shfl_xor(v, m, 64);
}

static __device__ __forceinline__ unsigned short f2bf(float f) {
    union { float f; unsigned u; } x; x.f = f;
    unsigned r = x.u + 0x7FFF + ((x.u >> 16) & 1);   // RTN-even
    return (unsigned short)(r >> 16);
}

// ---------------- K0: per-(c,k) stats: mu2, tau, log(tau), valid; rstd ----------------
__global__ void k_prep(const float* __restrict__ mu, const float* __restrict__ exp_temp,
                       const float* __restrict__ runa, const float* __restrict__ runb,
                       const float* __restrict__ stdv,
                       float* __restrict__ mu2, float* __restrict__ tauv,
                       float* __restrict__ ltau, float* __restrict__ vldf,
                       float* __restrict__ rstd)
{
    const int tid = threadIdx.x, w = tid >> 6, lane = tid & 63;
    if (blockIdx.x == 0) rstd[tid] = 1.0f / stdv[tid];   // blockDim==DDIM==256
    const int ck = blockIdx.x * 4 + w;
    if (ck >= CNUM * KNUM) return;
    const float4 v = *(const float4*)(mu + (size_t)ck * DDIM + lane * 4);
    float s = v.x * v.x + v.y * v.y + v.z * v.z + v.w * v.w;
#pragma unroll
    for (int off = 32; off > 0; off >>= 1) s += shfl_xor_f(s, off);
    if (lane == 0) {
        mu2[ck] = s;
        const float e = exp_temp[ck];
        const float t = 100.0f / (1.0f + __expf(-0.5f * e)) + 0.01f;
        tauv[ck] = t;
        ltau[ck] = logf(t);
        const int c = ck >> 6;
        const float thr = runb[c] * (0.5f / (float)KNUM);
        vldf[ck] = (runa[ck] > thr) ? 1.0f : 0.0f;
    }
}

// ---------------- K1: per-block class histogram (nb=64) ----------------
__global__ void k_hist(const int* __restrict__ labels, int N, int* __restrict__ bc)
{
    __shared__ int h[CNUM];
    const int tid = threadIdx.x;
    if (tid < CNUM) h[tid] = 0;
    __syncthreads();
    for (int i = blockIdx.x * blockDim.x + tid; i < N; i += gridDim.x * blockDim.x)
        atomicAdd(&h[labels[i]], 1);
    __syncthreads();
    if (tid < CNUM) bc[blockIdx.x * CNUM + tid] = h[tid];
}

// ---------------- K2: counts, padded class offsets, per-block scatter bases ----------------
__global__ void k_scan(const int* __restrict__ bc, int nb, int* __restrict__ cnt,
                       int* __restrict__ ps, int* __restrict__ sb)
{
    const int t = threadIdx.x;
    if (t < CNUM) {
        int s = 0;
#pragma unroll 8
        for (int b = 0; b < nb; b++) s += bc[b * CNUM + t];
        cnt[t] = s;
    }
    __syncthreads();
    if (t == 0) {
        int run = 0;
        for (int c = 0; c < CNUM; c++) { ps[c] = run; run += (cnt[c] + 63) & ~63; }
        ps[CNUM] = run;
    }
    __syncthreads();
    if (t < CNUM) {
        int run = ps[t];
#pragma unroll 8
        for (int b = 0; b < nb; b++) { sb[b * CNUM + t] = run; run += bc[b * CNUM + t]; }
    }
}

// ---------------- K3: scatter sample ids into class-sorted padded index array ----------------
__global__ void k_scatter(const int* __restrict__ labels, int N, const int* __restrict__ sb,
                          int* __restrict__ idx)
{
    __shared__ int cur[CNUM];
    const int tid = threadIdx.x;
    if (tid < CNUM) cur[tid] = sb[blockIdx.x * CNUM + tid];
    __syncthreads();
    for (int i = blockIdx.x * blockDim.x + tid; i < N; i += gridDim.x * blockDim.x) {
        const int c = labels[i];
        const int p = atomicAdd(&cur[c], 1);
        idx[p] = i;
    }
}

// ---------------- K4: main — 64 samples/block, one class/block, bf16 MFMA ----------------
__global__ __launch_bounds__(256, 2)
void k_main(const float* __restrict__ data, const float* __restrict__ mu,
            const float* __restrict__ med, const float* __restrict__ rstd,
            const float* __restrict__ mu2, const float* __restrict__ tauv,
            const float* __restrict__ ltau, const float* __restrict__ vldf,
            const int* __restrict__ idx, const int* __restrict__ ps,
            float* __restrict__ blockpart)
{
    __shared__ __align__(16) unsigned char smem[65536];  // X[64][256]bf16 | MU[64][256]bf16
    __shared__ float x2s[64];
    __shared__ float wred[4];
    unsigned char* __restrict__ Xb = smem;
    unsigned char* __restrict__ Ub = smem + 32768;
    float* __restrict__ simf = (float*)smem;             // [64][65] f32, overlays X

    const int tid = threadIdx.x, w = tid >> 6, lane = tid & 63;
    const int g = blockIdx.x;
    const int slot0 = g * 64;
    const int padtot = ps[CNUM];
    if (slot0 >= padtot) { if (tid == 0) blockpart[g] = 0.f; return; }
    int c = 0;
    while (c + 1 < CNUM && slot0 >= ps[c + 1]) ++c;

    // ---- stage X (normalized, bf16, swizzled) + per-row |x|^2 ----
    const int row = tid >> 2, sub = tid & 3;            // 64 rows x 4 subs
    const int swr = (row & 7) << 4;
    {
        const int n = idx[slot0 + row];
        const float act = (n >= 0) ? 1.0f : 0.0f;
        const int nn = (n >= 0) ? n : 0;
        const float* __restrict__ base = data + (size_t)nn * DDIM;
        float q = 0.f;
#pragma unroll
        for (int i = 0; i < 8; ++i) {
            const int d = 8 * (sub + 4 * i);            // 0..248
            const float4 u0 = *(const float4*)(base + d);
            const float4 u1 = *(const float4*)(base + d + 4);
            const float4 m0 = *(const float4*)(med + d);
            const float4 m1 = *(const float4*)(med + d + 4);
            const float4 r0 = *(const float4*)(rstd + d);
            const float4 r1 = *(const float4*)(rstd + d + 4);
            float a[8];
            a[0] = act * ((u0.x - m0.x) * r0.x); a[1] = act * ((u0.y - m0.y) * r0.y);
            a[2] = act * ((u0.z - m0.z) * r0.z); a[3] = act * ((u0.w - m0.w) * r0.w);
            a[4] = act * ((u1.x - m1.x) * r1.x); a[5] = act * ((u1.y - m1.y) * r1.y);
            a[6] = act * ((u1.z - m1.z) * r1.z); a[7] = act * ((u1.w - m1.w) * r1.w);
            u16x8 pk;
#pragma unroll
            for (int j = 0; j < 8; ++j) { q = fmaf(a[j], a[j], q); pk[j] = f2bf(a[j]); }
            *(u16x8*)(Xb + row * 512 + ((2 * d) ^ swr)) = pk;
        }
        q += shfl_xor_f(q, 1);
        q += shfl_xor_f(q, 2);
        if (sub == 0) x2s[row] = q;
    }
    // ---- stage MU (class tile, bf16, swizzled) ----
    {
        const float* __restrict__ base = mu + ((size_t)(c * KNUM + row)) * DDIM;
#pragma unroll
        for (int i = 0; i < 8; ++i) {
            const int d = 8 * (sub + 4 * i);
            const float4 u0 = *(const float4*)(base + d);
            const float4 u1 = *(const float4*)(base + d + 4);
            u16x8 pk;
            pk[0] = f2bf(u0.x); pk[1] = f2bf(u0.y); pk[2] = f2bf(u0.z); pk[3] = f2bf(u0.w);
            pk[4] = f2bf(u1.x); pk[5] = f2bf(u1.y); pk[6] = f2bf(u1.z); pk[7] = f2bf(u1.w);
            *(u16x8*)(Ub + row * 512 + ((2 * d) ^ swr)) = pk;
        }
    }
    __syncthreads();

    // ---- MFMA: wave w owns 32x32 quadrant (mr, nr); 2x2 frags of 16x16, K=256 ----
    const int mr = (w >> 1) & 1, nr = w & 1;
    const int lrow = lane & 15, kg = lane >> 4;          // A row / k-group
    f32x4 acc[2][2] = {};
#pragma unroll
    for (int s = 0; s < 8; ++s) {                        // K-step of 32
        const int kb = 64 * s + 16 * kg;                 // byte col of this lane's 8 bf16
        short8 af[2], bf[2];
#pragma unroll
        for (int fi = 0; fi < 2; ++fi) {
            const int ar = 32 * mr + 16 * fi + lrow;
            af[fi] = *(const short8*)(Xb + ar * 512 + (kb ^ ((ar & 7) << 4)));
        }
#pragma unroll
        for (int fj = 0; fj < 2; ++fj) {
            const int br = 32 * nr + 16 * fj + lrow;
            bf[fj] = *(const short8*)(Ub + br * 512 + (kb ^ ((br & 7) << 4)));
        }
#pragma unroll
        for (int fi = 0; fi < 2; ++fi)
#pragma unroll
            for (int fj = 0; fj < 2; ++fj)
                acc[fi][fj] = __builtin_amdgcn_mfma_f32_16x16x32_bf16(af[fi], bf[fj], acc[fi][fj], 0, 0, 0);
    }
    __syncthreads();   // everyone done reading X/MU

    // ---- write dots to simf[64][65] (overlays X) ----
#pragma unroll
    for (int fi = 0; fi < 2; ++fi)
#pragma unroll
        for (int fj = 0; fj < 2; ++fj)
#pragma unroll
            for (int r = 0; r < 4; ++r) {
                const int m = 32 * mr + 16 * fi + (lane >> 4) * 4 + r;
                const int n = 32 * nr + 16 * fj + (lane & 15);
                simf[m * 65 + n] = acc[fi][fj][r];
            }
    __syncthreads();

    // ---- phase 2: lane = k; wave w handles samples m in [w*16, w*16+16) ----
    const int ckb = c * KNUM;
    const float m2 = mu2[ckb + lane];
    const float tk = tauv[ckb + lane];
    const float lt = ltau[ckb + lane];
    const float vm = vldf[ckb + lane];
    float wacc = 0.f;
#pragma unroll 1
    for (int mi = 0; mi < 16; mi++) {
        const int m = w * 16 + mi;
        const int nm = idx[slot0 + m];
        if (nm < 0) continue;
        float d2 = x2s[m] + m2 - 2.0f * simf[m * 65 + lane];
        d2 = fmaxf(d2, 0.f);
        const float dist = -6.25f * sqrtf(d2);           // 100/sqrt(256)
        const float sim = (vm > 0.5f) ? dist : -1.0e12f;
        const float logit = 0.5f * sim;
        float mx = logit;
#pragma unroll
        for (int off = 32; off > 0; off >>= 1) mx = fmaxf(mx, shfl_xor_f(mx, off));
        const float e = __expf(logit - mx);
        const float lp = sim / tk - lt;
        float se = e, sl = e * lp;
#pragma unroll
        for (int off = 32; off > 0; off >>= 1) { se += shfl_xor_f(se, off); sl += shfl_xor_f(sl, off); }
        wacc -= sl / se;
    }
    __syncthreads();
    if (lane == 0) wred[w] = wacc;
    __syncthreads();
    if (tid == 0) blockpart[g] = ((wred[0] + wred[1]) + (wred[2] + wred[3]));
}

// ---------------- K5: deterministic per-class reduce -> loss ----------------
__global__ void k_final(const float* __restrict__ blockpart, const int* __restrict__ ps,
                        const int* __restrict__ cnt, float* __restrict__ out)
{
    __shared__ float seg[CNUM];
    const int t = threadIdx.x;
    if (t < CNUM) {
        float s = 0.f;
        const int b0 = ps[t] >> 6, b1 = ps[t + 1] >> 6;
        for (int b = b0; b < b1; b++) s += blockpart[b];
        seg[t] = s;
    }
    __syncthreads();
    if (t == 0) {
        float loss = 0.f;
        for (int c = 0; c < CNUM; c++) {
            const float cc = (float)cnt[c];
            if (cc > 0.f) loss += seg[c] / fmaxf(cc, 1.0f);
        }
        out[0] = loss;
    }
}

extern "C" void kernel_launch(void* const* d_in, const int* in_sizes, int n_in,
                              void* d_out, int out_size, void* d_ws, size_t ws_size,
                              hipStream_t stream)
{
    const float* data     = (const float*)d_in[0];
    const int*   labels   = (const int*)d_in[1];
    const float* mu       = (const float*)d_in[2];
    const float* exp_temp = (const float*)d_in[3];
    const float* med      = (const float*)d_in[4];
    const float* stdv     = (const float*)d_in[5];
    const float* runa     = (const float*)d_in[6];
    const float* runb     = (const float*)d_in[7];
    float* out = (float*)d_out;
    const int N = in_sizes[0] / DDIM;
    const int NHB = 64;   // histogram/scatter blocks

    char* w = (char*)d_ws;
    float* mu2  = (float*)w; w += (size_t)CNUM * KNUM * 4;
    float* tauv = (float*)w; w += (size_t)CNUM * KNUM * 4;
    float* ltau = (float*)w; w += (size_t)CNUM * KNUM * 4;
    float* vldf = (float*)w; w += (size_t)CNUM * KNUM * 4;
    float* rstd = (float*)w; w += (size_t)DDIM * 4;
    int* bc  = (int*)w; w += (size_t)NHB * CNUM * 4;
    int* sb  = (int*)w; w += (size_t)NHB * CNUM * 4;
    int* cnt = (int*)w; w += 64 * 4;
    int* ps  = (int*)w; w += 64 * 4;
    const int idx_slots = N + CNUM * 64;
    int* idx = (int*)w; w += (size_t)idx_slots * 4;
    const int NB = (idx_slots + 63) / 64;
    float* bp = (float*)w; w += (size_t)NB * 4;

    k_prep<<<dim3((CNUM * KNUM + 3) / 4), dim3(256), 0, stream>>>(
        mu, exp_temp, runa, runb, stdv, mu2, tauv, ltau, vldf, rstd);
    k_hist<<<dim3(NHB), dim3(256), 0, stream>>>(labels, N, bc);
    k_scan<<<dim3(1), dim3(64), 0, stream>>>(bc, NHB, cnt, ps, sb);
    hipMemsetAsync(idx, 0xFF, (size_t)idx_slots * 4, stream);   // idx = -1 (padding)
    k_scatter<<<dim3(NHB), dim3(256), 0, stream>>>(labels, N, sb, idx);
    k_main<<<dim3(NB), dim3(256), 0, stream>>>(
        data, mu, med, rstd, mu2, tauv, ltau, vldf, idx, ps, bp);
    k_final<<<dim3(1), dim3(32), 0, stream>>>(bp, ps, cnt, out);
}